// Round 5
// baseline (348.749 us; speedup 1.0000x reference)
//
#include <hip/hip_runtime.h>
#include <hip/hip_bf16.h>

typedef __bf16 bf16x8 __attribute__((ext_vector_type(8)));
typedef float f32x4 __attribute__((ext_vector_type(4)));

#define MFMA_BF16(A, B, C) __builtin_amdgcn_mfma_f32_16x16x32_bf16((A), (B), (C), 0, 0, 0)

namespace cfg {
constexpr int NB = 512;                // graphs
constexpr int NPG = 64;                // nodes per graph
constexpr int EPG = 256;               // edges per graph
constexpr int FN = 128, FE = 64, FG = 64;
constexpr int XP  = 2 * FN + FE + FG;  // 384  message-MLP input width
constexpr int XPP = XP + 8;            // 392  padded pitch (ushorts)
constexpr int HPP = 256 + 8;           // 264  hidden/output pitch
constexpr int X2P  = FN + 256 + FG;    // 448  update-MLP input width
constexpr int X2PP = X2P + 8;          // 456
// LDS byte offsets (fused kernel)
constexpr int OFF_XS1 = 0;                        // [64][392] ush = 50,176 B (phase1)
constexpr int OFF_HS1 = 64 * XPP * 2;             // 50,176: [64][264] ush = 33,792 B (phase1)
constexpr int OFF_X2  = 0;                        // [64][456] ush = 58,368 B (phase2, over Xs1/Hs1)
constexpr int OFF_US  = 0;                        // [64][264] ush (phase2 late, over dead X2)
constexpr int OFF_AG  = 64 * XPP * 2 + 64 * HPP * 2;  // 83,968: [64][256] u32 = 65,536 B
constexpr int OFF_HS2 = OFF_AG;                   // phase2: over dead Ag
constexpr int OFF_TL  = OFF_AG + 64 * 256 * 4;    // 149,504: [64] int
constexpr int OFF_PS  = OFF_TL + 256;             // 149,760: [256] f32
constexpr int OFF_GS  = OFF_PS + 1024;            // 150,784: [128] f32
constexpr int OFF_LS  = OFF_GS + 512;             // 151,296: [8] f32
constexpr int LDS_TOTAL = OFF_LS + 32;            // 151,328 B < 160 KiB
}

__device__ __forceinline__ ushort f2bf(float f) {
  union { float f; unsigned u; } x; x.f = f;
  unsigned r = x.u + 0x7FFFu + ((x.u >> 16) & 1u);   // RNE
  return (ushort)(r >> 16);
}
__device__ __forceinline__ float bf2f(ushort u) {
  union { unsigned u; float f; } x; x.u = ((unsigned)u) << 16; return x.f;
}
__device__ __forceinline__ void cvt8(const float* __restrict__ s, ushort* d) {
  float4 a = *(const float4*)s, b = *(const float4*)(s + 4);
  d[0] = f2bf(a.x); d[1] = f2bf(a.y); d[2] = f2bf(a.z); d[3] = f2bf(a.w);
  d[4] = f2bf(b.x); d[5] = f2bf(b.y); d[6] = f2bf(b.z); d[7] = f2bf(b.w);
}

// ---------- weight transpose + f32->bf16: in[R][C] f32 -> out[C][R] bf16 ----------
__global__ void ktrans_cvt(const float* __restrict__ in, ushort* __restrict__ out,
                           int R, int C) {
  __shared__ float t[32][33];
  const int c0 = blockIdx.x * 32, r0 = blockIdx.y * 32;
  const int tx = threadIdx.x & 31, ty = threadIdx.x >> 5;   // 32 x 8
#pragma unroll
  for (int i = 0; i < 32; i += 8) {
    int r = r0 + ty + i, c = c0 + tx;
    t[ty + i][tx] = (r < R && c < C) ? in[(size_t)r * C + c] : 0.f;
  }
  __syncthreads();
#pragma unroll
  for (int i = 0; i < 32; i += 8) {
    int c = c0 + ty + i, r = r0 + tx;
    if (c < C && r < R) out[(size_t)c * R + r] = f2bf(t[tx][ty + i]);
  }
}

// ---------------- fused per-graph MPN: message+scatter-max+update+heads ----------------
// block = 512 threads (8 waves), grid = 512 graphs. Dynamic LDS per cfg offsets.
__launch_bounds__(512, 2)
__global__ void k_fused(const float* __restrict__ nodes,
                        const float* __restrict__ eattr,
                        const float* __restrict__ glob,
                        const int* __restrict__ srci,
                        const int* __restrict__ tgti,
                        const int* __restrict__ tbw,
                        const ushort* __restrict__ WTm0,  // [512][384] bf16
                        const float* __restrict__ bm0,
                        const ushort* __restrict__ WTm1,  // [256][512]
                        const float* __restrict__ bm1,
                        const ushort* __restrict__ WTu0,  // [512][448]
                        const float* __restrict__ bu0,
                        const ushort* __restrict__ WTu1,  // [256][512]
                        const float* __restrict__ bu1,
                        const ushort* __restrict__ WTg,   // [128][320]
                        const float* __restrict__ bg,
                        const ushort* __restrict__ WTa,   // [8][384]
                        const float* __restrict__ ba,
                        float* __restrict__ out)          // [B][8] f32
{
  using namespace cfg;
  extern __shared__ __align__(16) char smem[];
  ushort*   Xs1 = (ushort*)(smem + OFF_XS1);
  ushort*   Hs1 = (ushort*)(smem + OFF_HS1);
  ushort*   X2  = (ushort*)(smem + OFF_X2);
  ushort*   Us  = (ushort*)(smem + OFF_US);
  unsigned* Ag  = (unsigned*)(smem + OFF_AG);
  ushort*   Hs2 = (ushort*)(smem + OFF_HS2);
  int*      tl  = (int*)(smem + OFF_TL);
  float*    Ps  = (float*)(smem + OFF_PS);
  float*    Gs  = (float*)(smem + OFF_GS);
  float*    Ls  = (float*)(smem + OFF_LS);

  const int g    = blockIdx.x;
  const int tid  = threadIdx.x;
  const int lane = tid & 63;
  const int wv   = tid >> 6;        // 0..7
  const int l16  = lane & 15;
  const int l4   = lane >> 4;

  // ---------------- phase 1: message MLP over 4 edge sub-tiles ----------------
  for (int i = tid; i < 64 * 256; i += 512) Ag[i] = 0u;

  for (int t = 0; t < 4; ++t) {
    const int e0 = g * EPG + t * 64;
    __syncthreads();                 // Ag init / prev subtile scatter + tl reads done
    if (tid < 64) tl[tid] = tgti[e0 + tid] - g * NPG;
    // gather X (f32 -> bf16): 64 rows x 48 chunks of 8
    for (int li = tid; li < 64 * 48; li += 512) {
      int r = li / 48, c = li % 48;
      int e = e0 + r;
      const float* src;
      if (c < 16)       src = nodes + (size_t)srci[e] * FN + c * 8;
      else if (c < 24)  src = eattr + (size_t)e * FE + (c - 16) * 8;
      else if (c < 40)  src = nodes + (size_t)tgti[e] * FN + (c - 24) * 8;
      else              src = glob + (size_t)g * FG + (c - 40) * 8;
      alignas(16) ushort tmp[8];
      cvt8(src, tmp);
      *(uint4*)(Xs1 + r * XPP + c * 8) = *(const uint4*)tmp;
    }
    __syncthreads();                 // Xs1, tl visible

    f32x4 acc2[4][2] = {};           // message [64 rows][this wave's 32 cols]

    for (int h = 0; h < 2; ++h) {    // layer-1 N halves (512 = 2*256)
      f32x4 acc1[4][2] = {};
#pragma unroll 2
      for (int k = 0; k < XP; k += 32) {
        bf16x8 af[4], bw[2];
#pragma unroll
        for (int m = 0; m < 4; ++m)
          af[m] = *(const bf16x8*)(Xs1 + (m * 16 + l16) * XPP + k + 8 * l4);
#pragma unroll
        for (int n = 0; n < 2; ++n) {
          int nc = h * 256 + wv * 32 + n * 16 + l16;
          bw[n] = *(const bf16x8*)(WTm0 + (size_t)nc * XP + k + 8 * l4);
        }
#pragma unroll
        for (int m = 0; m < 4; ++m)
#pragma unroll
          for (int n = 0; n < 2; ++n)
            acc1[m][n] = MFMA_BF16(af[m], bw[n], acc1[m][n]);
      }
      __syncthreads();               // prior readers of Hs1 done
#pragma unroll
      for (int n = 0; n < 2; ++n) {
        int col = wv * 32 + n * 16 + l16;
        float bb = bm0[h * 256 + col];
#pragma unroll
        for (int m = 0; m < 4; ++m)
#pragma unroll
          for (int j = 0; j < 4; ++j) {
            float v = acc1[m][n][j] + bb;
            Hs1[(m * 16 + l4 * 4 + j) * HPP + col] = f2bf(v > 0.f ? v : 0.f);
          }
      }
      __syncthreads();               // Hs1 visible
#pragma unroll 2
      for (int k = 0; k < 256; k += 32) {
        bf16x8 af[4], bw[2];
#pragma unroll
        for (int m = 0; m < 4; ++m)
          af[m] = *(const bf16x8*)(Hs1 + (m * 16 + l16) * HPP + k + 8 * l4);
#pragma unroll
        for (int n = 0; n < 2; ++n) {
          int nc = wv * 32 + n * 16 + l16;
          bw[n] = *(const bf16x8*)(WTm1 + (size_t)nc * 512 + h * 256 + k + 8 * l4);
        }
#pragma unroll
        for (int m = 0; m < 4; ++m)
#pragma unroll
          for (int n = 0; n < 2; ++n)
            acc2[m][n] = MFMA_BF16(af[m], bw[n], acc2[m][n]);
      }
    }
    // scatter-max into Ag (messages >= 0; uint-bit order exact; init-0 == clamp)
#pragma unroll
    for (int n = 0; n < 2; ++n) {
      int col = wv * 32 + n * 16 + l16;
      float bb = bm1[col];
#pragma unroll
      for (int m = 0; m < 4; ++m)
#pragma unroll
        for (int j = 0; j < 4; ++j) {
          float v = acc2[m][n][j] + bb;
          if (v > 0.f) {
            int row = m * 16 + l4 * 4 + j;
            atomicMax(&Ag[tl[row] * 256 + col], __float_as_uint(v));
          }
        }
    }
  }
  __syncthreads();                   // Ag complete; Xs1/Hs1 dead

  // ---------------- phase 2: node update MLP ----------------
  // gather X2 = [nodes | aggr | glob] (bf16), 64 rows x 56 chunks of 8
  for (int li = tid; li < 64 * 56; li += 512) {
    int r = li / 56, c = li % 56;
    alignas(16) ushort tmp[8];
    if (c >= 16 && c < 48) {
      const unsigned* a = Ag + r * 256 + (c - 16) * 8;
#pragma unroll
      for (int j = 0; j < 8; ++j) tmp[j] = f2bf(__uint_as_float(a[j]));
    } else {
      const float* src = (c < 16) ? nodes + (size_t)(g * 64 + r) * FN + c * 8
                                  : glob + (size_t)g * FG + (c - 48) * 8;
      cvt8(src, tmp);
    }
    *(uint4*)(X2 + r * X2PP + c * 8) = *(const uint4*)tmp;
  }
  __syncthreads();                   // X2 visible; Ag dead (Hs2 may now use it)

  {
    f32x4 acc2u[4][2] = {};
    for (int h = 0; h < 2; ++h) {
      f32x4 acc1[4][2] = {};
#pragma unroll 2
      for (int k = 0; k < X2P; k += 32) {
        bf16x8 af[4], bw[2];
#pragma unroll
        for (int m = 0; m < 4; ++m)
          af[m] = *(const bf16x8*)(X2 + (m * 16 + l16) * X2PP + k + 8 * l4);
#pragma unroll
        for (int n = 0; n < 2; ++n) {
          int nc = h * 256 + wv * 32 + n * 16 + l16;
          bw[n] = *(const bf16x8*)(WTu0 + (size_t)nc * X2P + k + 8 * l4);
        }
#pragma unroll
        for (int m = 0; m < 4; ++m)
#pragma unroll
          for (int n = 0; n < 2; ++n)
            acc1[m][n] = MFMA_BF16(af[m], bw[n], acc1[m][n]);
      }
      __syncthreads();               // h=0: Ag readers done; h=1: Hs2 readers done
#pragma unroll
      for (int n = 0; n < 2; ++n) {
        int col = wv * 32 + n * 16 + l16;
        float bb = bu0[h * 256 + col];
#pragma unroll
        for (int m = 0; m < 4; ++m)
#pragma unroll
          for (int j = 0; j < 4; ++j) {
            float v = acc1[m][n][j] + bb;
            Hs2[(m * 16 + l4 * 4 + j) * HPP + col] = f2bf(v > 0.f ? v : 0.f);
          }
      }
      __syncthreads();               // Hs2 visible
#pragma unroll 2
      for (int k = 0; k < 256; k += 32) {
        bf16x8 af[4], bw[2];
#pragma unroll
        for (int m = 0; m < 4; ++m)
          af[m] = *(const bf16x8*)(Hs2 + (m * 16 + l16) * HPP + k + 8 * l4);
#pragma unroll
        for (int n = 0; n < 2; ++n) {
          int nc = wv * 32 + n * 16 + l16;
          bw[n] = *(const bf16x8*)(WTu1 + (size_t)nc * 512 + h * 256 + k + 8 * l4);
        }
#pragma unroll
        for (int m = 0; m < 4; ++m)
#pragma unroll
          for (int n = 0; n < 2; ++n)
            acc2u[m][n] = MFMA_BF16(af[m], bw[n], acc2u[m][n]);
      }
    }
    // upd (relu) -> Us (aliases dead X2: all waves are past X2 reads, 2 barriers ago)
#pragma unroll
    for (int n = 0; n < 2; ++n) {
      int col = wv * 32 + n * 16 + l16;
      float bb = bu1[col];
#pragma unroll
      for (int m = 0; m < 4; ++m)
#pragma unroll
        for (int j = 0; j < 4; ++j) {
          float v = acc2u[m][n][j] + bb;
          Us[(m * 16 + l4 * 4 + j) * HPP + col] = f2bf(v > 0.f ? v : 0.f);
        }
    }
  }
  __syncthreads();                   // Us visible

  // ---------------- heads ----------------
  if (tid < 256) {                   // pooled max over 64 rows (upd >= 0)
    float mx = 0.f;
    for (int r = 0; r < 64; ++r) mx = fmaxf(mx, bf2f(Us[r * HPP + tid]));
    Ps[tid] = mx;
  }
  __syncthreads();

  // group = relu([pooled, global] @ W_g + b_g): 8 waves x 16 outputs
  for (int jj = 0; jj < 16; ++jj) {
    int j = wv * 16 + jj;
    const ushort* wr = WTg + (size_t)j * 320;
    float part = 0.f;
    for (int k = lane; k < 320; k += 64) {
      float x = (k < 256) ? Ps[k] : glob[(size_t)g * FG + (k - 256)];
      part += x * bf2f(wr[k]);
    }
#pragma unroll
    for (int o = 32; o > 0; o >>= 1) part += __shfl_down(part, o);
    if (lane == 0) {
      float v = part + bg[j];
      Gs[j] = v > 0.f ? v : 0.f;
    }
  }
  __syncthreads();

  // logits: wave w computes logit w
  {
    const int tb = tbw[g] - g * 64;
    const ushort* wr = WTa + (size_t)wv * 384;
    float part = 0.f;
    for (int k = lane; k < 384; k += 64) {
      float x = (k < 256) ? bf2f(Us[tb * HPP + k]) : Gs[k - 256];
      part += x * bf2f(wr[k]);
    }
#pragma unroll
    for (int o = 32; o > 0; o >>= 1) part += __shfl_down(part, o);
    if (lane == 0) Ls[wv] = part + ba[wv];
  }
  __syncthreads();

  if (tid == 0) {
    float mx = Ls[0];
#pragma unroll
    for (int i = 1; i < 8; ++i) mx = fmaxf(mx, Ls[i]);
    float e[8], sum = 0.f;
#pragma unroll
    for (int i = 0; i < 8; ++i) { e[i] = __expf(Ls[i] - mx); sum += e[i]; }
    float inv = 1.f / sum;
#pragma unroll
    for (int i = 0; i < 8; ++i) out[(size_t)g * 8 + i] = e[i] * inv;
  }
}

// ---------------- launch ----------------
extern "C" void kernel_launch(void* const* d_in, const int* in_sizes, int n_in,
                              void* d_out, int out_size, void* d_ws, size_t ws_size,
                              hipStream_t stream) {
  (void)in_sizes; (void)n_in; (void)out_size; (void)ws_size;
  using namespace cfg;
  const float* nodes = (const float*)d_in[0];
  const float* eattr = (const float*)d_in[1];
  const float* glob  = (const float*)d_in[2];
  const int* srci = (const int*)d_in[3];
  const int* tgti = (const int*)d_in[4];
  const int* tbw  = (const int*)d_in[7];
  const float* W_m0 = (const float*)d_in[8];
  const float* b_m0 = (const float*)d_in[9];
  const float* W_m1 = (const float*)d_in[10];
  const float* b_m1 = (const float*)d_in[11];
  const float* W_u0 = (const float*)d_in[12];
  const float* b_u0 = (const float*)d_in[13];
  const float* W_u1 = (const float*)d_in[14];
  const float* b_u1 = (const float*)d_in[15];
  const float* W_g  = (const float*)d_in[16];
  const float* b_g  = (const float*)d_in[17];
  const float* W_a  = (const float*)d_in[18];
  const float* b_a  = (const float*)d_in[19];

  char* ws = (char*)d_ws;
  size_t off = 0;
  auto alloc = [&](size_t bytes) {
    char* p = ws + off; off += (bytes + 255) & ~(size_t)255; return p;
  };
  ushort* WTm0 = (ushort*)alloc((size_t)512 * 384 * 2);
  ushort* WTm1 = (ushort*)alloc((size_t)256 * 512 * 2);
  ushort* WTu0 = (ushort*)alloc((size_t)512 * 448 * 2);
  ushort* WTu1 = (ushort*)alloc((size_t)256 * 512 * 2);
  ushort* WTg  = (ushort*)alloc((size_t)128 * 320 * 2);
  ushort* WTa  = (ushort*)alloc((size_t)8 * 384 * 2);

  dim3 tb(256);
  auto T = [&](const float* in, ushort* outp, int R, int C) {
    ktrans_cvt<<<dim3((C + 31) / 32, (R + 31) / 32), tb, 0, stream>>>(in, outp, R, C);
  };
  T(W_m0, WTm0, 384, 512);
  T(W_m1, WTm1, 512, 256);
  T(W_u0, WTu0, 448, 512);
  T(W_u1, WTu1, 512, 256);
  T(W_g,  WTg,  320, 128);
  T(W_a,  WTa,  384, 8);

  hipFuncSetAttribute((const void*)k_fused, hipFuncAttributeMaxDynamicSharedMemorySize,
                      (int)LDS_TOTAL);
  k_fused<<<NB, 512, LDS_TOTAL, stream>>>(nodes, eattr, glob, srci, tgti, tbw,
                                          WTm0, b_m0, WTm1, b_m1,
                                          WTu0, b_u0, WTu1, b_u1,
                                          WTg, b_g, WTa, b_a, (float*)d_out);
}

// Round 6
// 296.984 us; speedup vs baseline: 1.1743x; 1.1743x over previous
//
#include <hip/hip_runtime.h>
#include <hip/hip_bf16.h>

typedef __bf16 bf16x8 __attribute__((ext_vector_type(8)));
typedef float f32x4 __attribute__((ext_vector_type(4)));

#define MFMA_BF16(A, B, C) __builtin_amdgcn_mfma_f32_16x16x32_bf16((A), (B), (C), 0, 0, 0)

namespace cfg {
constexpr int NB = 512;                // graphs
constexpr int NPG = 64;                // nodes per graph
constexpr int EPG = 256;               // edges per graph
constexpr int FN = 128, FE = 64, FG = 64;
constexpr int XP  = 2 * FN + FE + FG;  // 384  message-MLP input width
constexpr int XPP = XP + 8;            // 392  padded pitch (ushorts)
constexpr int HPP = 256 + 8;           // 264  hidden/output pitch
constexpr int X2P  = FN + 256 + FG;    // 448  update-MLP input width
constexpr int X2PP = X2P + 8;          // 456
// LDS byte offsets (fused kernel)
constexpr int OFF_XS1 = 0;                        // [64][392] ush (phase1)
constexpr int OFF_HS1 = 64 * XPP * 2;             // [64][264] ush (phase1)
constexpr int OFF_X2  = 0;                        // [64][456] ush (phase2, over Xs1/Hs1)
constexpr int OFF_US  = 0;                        // [64][264] ush (phase2 late, over dead X2)
constexpr int OFF_AG  = 64 * XPP * 2 + 64 * HPP * 2;  // [64][256] u32
constexpr int OFF_HS2 = OFF_AG;                   // phase2: over dead Ag
constexpr int OFF_TL  = OFF_AG + 64 * 256 * 4;    // [64] int
constexpr int OFF_PS  = OFF_TL + 256;             // [256] f32
constexpr int OFF_GS  = OFF_PS + 1024;            // [128] f32
constexpr int OFF_LS  = OFF_GS + 512;             // [8] f32
constexpr int LDS_TOTAL = OFF_LS + 32;            // 151,328 B < 160 KiB -> 1 block/CU
}

__device__ __forceinline__ ushort f2bf(float f) {
  union { float f; unsigned u; } x; x.f = f;
  unsigned r = x.u + 0x7FFFu + ((x.u >> 16) & 1u);   // RNE
  return (ushort)(r >> 16);
}
__device__ __forceinline__ float bf2f(ushort u) {
  union { unsigned u; float f; } x; x.u = ((unsigned)u) << 16; return x.f;
}
__device__ __forceinline__ void cvt8(const float* __restrict__ s, ushort* d) {
  float4 a = *(const float4*)s, b = *(const float4*)(s + 4);
  d[0] = f2bf(a.x); d[1] = f2bf(a.y); d[2] = f2bf(a.z); d[3] = f2bf(a.w);
  d[4] = f2bf(b.x); d[5] = f2bf(b.y); d[6] = f2bf(b.z); d[7] = f2bf(b.w);
}

// ---------- weight transpose + f32->bf16: in[R][C] f32 -> out[C][R] bf16 ----------
__global__ void ktrans_cvt(const float* __restrict__ in, ushort* __restrict__ out,
                           int R, int C) {
  __shared__ float t[32][33];
  const int c0 = blockIdx.x * 32, r0 = blockIdx.y * 32;
  const int tx = threadIdx.x & 31, ty = threadIdx.x >> 5;   // 32 x 8
#pragma unroll
  for (int i = 0; i < 32; i += 8) {
    int r = r0 + ty + i, c = c0 + tx;
    t[ty + i][tx] = (r < R && c < C) ? in[(size_t)r * C + c] : 0.f;
  }
  __syncthreads();
#pragma unroll
  for (int i = 0; i < 32; i += 8) {
    int c = c0 + ty + i, r = r0 + tx;
    if (c < C && r < R) out[(size_t)c * R + r] = f2bf(t[tx][ty + i]);
  }
}

// ---------------- fused per-graph MPN: message+scatter-max+update+heads ----------------
// block = 1024 threads (16 waves, 4/SIMD), grid = 512 graphs.
// Wave wv owns output cols [wv*16, wv*16+16) of each 256-wide GEMM half.
__launch_bounds__(1024, 4)
__global__ void k_fused(const float* __restrict__ nodes,
                        const float* __restrict__ eattr,
                        const float* __restrict__ glob,
                        const int* __restrict__ srci,
                        const int* __restrict__ tgti,
                        const int* __restrict__ tbw,
                        const ushort* __restrict__ WTm0,  // [512][384] bf16
                        const float* __restrict__ bm0,
                        const ushort* __restrict__ WTm1,  // [256][512]
                        const float* __restrict__ bm1,
                        const ushort* __restrict__ WTu0,  // [512][448]
                        const float* __restrict__ bu0,
                        const ushort* __restrict__ WTu1,  // [256][512]
                        const float* __restrict__ bu1,
                        const ushort* __restrict__ WTg,   // [128][320]
                        const float* __restrict__ bg,
                        const ushort* __restrict__ WTa,   // [8][384]
                        const float* __restrict__ ba,
                        float* __restrict__ out)          // [B][8] f32
{
  using namespace cfg;
  extern __shared__ __align__(16) char smem[];
  ushort*   Xs1 = (ushort*)(smem + OFF_XS1);
  ushort*   Hs1 = (ushort*)(smem + OFF_HS1);
  ushort*   X2  = (ushort*)(smem + OFF_X2);
  ushort*   Us  = (ushort*)(smem + OFF_US);
  unsigned* Ag  = (unsigned*)(smem + OFF_AG);
  ushort*   Hs2 = (ushort*)(smem + OFF_HS2);
  int*      tl  = (int*)(smem + OFF_TL);
  float*    Ps  = (float*)(smem + OFF_PS);
  float*    Gs  = (float*)(smem + OFF_GS);
  float*    Ls  = (float*)(smem + OFF_LS);

  const int g    = blockIdx.x;
  const int tid  = threadIdx.x;
  const int lane = tid & 63;
  const int wv   = tid >> 6;        // 0..15
  const int l16  = lane & 15;
  const int l4   = lane >> 4;
  const int col  = wv * 16 + l16;   // this lane's output column (0..255)

  // ---------------- phase 1: message MLP over 4 edge sub-tiles ----------------
  for (int i = tid; i < 64 * 256; i += 1024) Ag[i] = 0u;

  // T14 async-stage: tile gather goes global->regs early, regs->LDS after barrier.
  float4 pa[3], pb[3]; int ptl = 0;
  auto load_tile = [&](int t) {
    const int e0g = g * EPG + t * 64;
#pragma unroll
    for (int i = 0; i < 3; ++i) {
      int li = tid + i * 1024;      // 3072 chunks = 64 rows x 48
      int r = li / 48, c = li % 48;
      int e = e0g + r;
      const float* src;
      if (c < 16)       src = nodes + (size_t)srci[e] * FN + c * 8;
      else if (c < 24)  src = eattr + (size_t)e * FE + (c - 16) * 8;
      else if (c < 40)  src = nodes + (size_t)tgti[e] * FN + (c - 24) * 8;
      else              src = glob + (size_t)g * FG + (c - 40) * 8;
      pa[i] = *(const float4*)src;
      pb[i] = *(const float4*)(src + 4);
    }
    if (tid < 64) ptl = tgti[e0g + tid] - g * NPG;
  };
  auto store_tile = [&]() {
#pragma unroll
    for (int i = 0; i < 3; ++i) {
      int li = tid + i * 1024;
      int r = li / 48, c = li % 48;
      alignas(16) ushort tmp[8];
      tmp[0] = f2bf(pa[i].x); tmp[1] = f2bf(pa[i].y);
      tmp[2] = f2bf(pa[i].z); tmp[3] = f2bf(pa[i].w);
      tmp[4] = f2bf(pb[i].x); tmp[5] = f2bf(pb[i].y);
      tmp[6] = f2bf(pb[i].z); tmp[7] = f2bf(pb[i].w);
      *(uint4*)(Xs1 + r * XPP + c * 8) = *(const uint4*)tmp;
    }
    if (tid < 64) tl[tid] = ptl;
  };

  load_tile(0);
  for (int t = 0; t < 4; ++t) {
    __syncthreads();                 // prev tile fully consumed (Xs1/tl reads, Ag scatter)
    store_tile();
    if (t < 3) load_tile(t + 1);     // issue next-tile loads; they complete under compute
    __syncthreads();                 // Xs1, tl visible

    f32x4 acc2[4] = {};              // message [4 row-frags][this wave's 16 cols]

    for (int h = 0; h < 2; ++h) {    // layer-1 N halves (512 = 2*256)
      f32x4 acc1[4] = {};
#pragma unroll 2
      for (int k = 0; k < XP; k += 32) {
        bf16x8 af[4], bw;
#pragma unroll
        for (int m = 0; m < 4; ++m)
          af[m] = *(const bf16x8*)(Xs1 + (m * 16 + l16) * XPP + k + 8 * l4);
        bw = *(const bf16x8*)(WTm0 + (size_t)(h * 256 + col) * XP + k + 8 * l4);
#pragma unroll
        for (int m = 0; m < 4; ++m)
          acc1[m] = MFMA_BF16(af[m], bw, acc1[m]);
      }
      __syncthreads();               // prior readers of Hs1 done
      {
        float bb = bm0[h * 256 + col];
#pragma unroll
        for (int m = 0; m < 4; ++m)
#pragma unroll
          for (int j = 0; j < 4; ++j) {
            float v = acc1[m][j] + bb;
            Hs1[(m * 16 + l4 * 4 + j) * HPP + col] = f2bf(v > 0.f ? v : 0.f);
          }
      }
      __syncthreads();               // Hs1 visible
#pragma unroll 2
      for (int k = 0; k < 256; k += 32) {
        bf16x8 af[4], bw;
#pragma unroll
        for (int m = 0; m < 4; ++m)
          af[m] = *(const bf16x8*)(Hs1 + (m * 16 + l16) * HPP + k + 8 * l4);
        bw = *(const bf16x8*)(WTm1 + (size_t)col * 512 + h * 256 + k + 8 * l4);
#pragma unroll
        for (int m = 0; m < 4; ++m)
          acc2[m] = MFMA_BF16(af[m], bw, acc2[m]);
      }
    }
    // scatter-max into Ag (messages >= 0; uint-bit order exact; init-0 == clamp)
    {
      float bb = bm1[col];
#pragma unroll
      for (int m = 0; m < 4; ++m)
#pragma unroll
        for (int j = 0; j < 4; ++j) {
          float v = acc2[m][j] + bb;
          if (v > 0.f) {
            int row = m * 16 + l4 * 4 + j;
            atomicMax(&Ag[tl[row] * 256 + col], __float_as_uint(v));
          }
        }
    }
  }
  __syncthreads();                   // Ag complete; Xs1/Hs1 dead

  // ---------------- phase 2: node update MLP ----------------
  // gather X2 = [nodes | aggr | glob] (bf16), 64 rows x 56 chunks of 8
  for (int li = tid; li < 64 * 56; li += 1024) {
    int r = li / 56, c = li % 56;
    alignas(16) ushort tmp[8];
    if (c >= 16 && c < 48) {
      const unsigned* a = Ag + r * 256 + (c - 16) * 8;
#pragma unroll
      for (int j = 0; j < 8; ++j) tmp[j] = f2bf(__uint_as_float(a[j]));
    } else {
      const float* src = (c < 16) ? nodes + (size_t)(g * 64 + r) * FN + c * 8
                                  : glob + (size_t)g * FG + (c - 48) * 8;
      cvt8(src, tmp);
    }
    *(uint4*)(X2 + r * X2PP + c * 8) = *(const uint4*)tmp;
  }
  __syncthreads();                   // X2 visible; Ag dead (Hs2 may now use it)

  {
    f32x4 acc2u[4] = {};
    for (int h = 0; h < 2; ++h) {
      f32x4 acc1[4] = {};
#pragma unroll 2
      for (int k = 0; k < X2P; k += 32) {
        bf16x8 af[4], bw;
#pragma unroll
        for (int m = 0; m < 4; ++m)
          af[m] = *(const bf16x8*)(X2 + (m * 16 + l16) * X2PP + k + 8 * l4);
        bw = *(const bf16x8*)(WTu0 + (size_t)(h * 256 + col) * X2P + k + 8 * l4);
#pragma unroll
        for (int m = 0; m < 4; ++m)
          acc1[m] = MFMA_BF16(af[m], bw, acc1[m]);
      }
      __syncthreads();               // h=0: Ag readers done; h=1: Hs2 readers done
      {
        float bb = bu0[h * 256 + col];
#pragma unroll
        for (int m = 0; m < 4; ++m)
#pragma unroll
          for (int j = 0; j < 4; ++j) {
            float v = acc1[m][j] + bb;
            Hs2[(m * 16 + l4 * 4 + j) * HPP + col] = f2bf(v > 0.f ? v : 0.f);
          }
      }
      __syncthreads();               // Hs2 visible
#pragma unroll 2
      for (int k = 0; k < 256; k += 32) {
        bf16x8 af[4], bw;
#pragma unroll
        for (int m = 0; m < 4; ++m)
          af[m] = *(const bf16x8*)(Hs2 + (m * 16 + l16) * HPP + k + 8 * l4);
        bw = *(const bf16x8*)(WTu1 + (size_t)col * 512 + h * 256 + k + 8 * l4);
#pragma unroll
        for (int m = 0; m < 4; ++m)
          acc2u[m] = MFMA_BF16(af[m], bw, acc2u[m]);
      }
    }
    // upd (relu) -> Us (aliases dead X2: last X2 read was 2 barriers ago)
    {
      float bb = bu1[col];
#pragma unroll
      for (int m = 0; m < 4; ++m)
#pragma unroll
        for (int j = 0; j < 4; ++j) {
          float v = acc2u[m][j] + bb;
          Us[(m * 16 + l4 * 4 + j) * HPP + col] = f2bf(v > 0.f ? v : 0.f);
        }
    }
  }
  __syncthreads();                   // Us visible

  // ---------------- heads ----------------
  if (tid < 256) {                   // pooled max over 64 rows (upd >= 0)
    float mx = 0.f;
    for (int r = 0; r < 64; ++r) mx = fmaxf(mx, bf2f(Us[r * HPP + tid]));
    Ps[tid] = mx;
  }
  __syncthreads();

  // group = relu([pooled, global] @ W_g + b_g): 16 waves x 8 outputs
  for (int jj = 0; jj < 8; ++jj) {
    int j = wv * 8 + jj;
    const ushort* wr = WTg + (size_t)j * 320;
    float part = 0.f;
    for (int k = lane; k < 320; k += 64) {
      float x = (k < 256) ? Ps[k] : glob[(size_t)g * FG + (k - 256)];
      part += x * bf2f(wr[k]);
    }
#pragma unroll
    for (int o = 32; o > 0; o >>= 1) part += __shfl_down(part, o);
    if (lane == 0) {
      float v = part + bg[j];
      Gs[j] = v > 0.f ? v : 0.f;
    }
  }
  __syncthreads();

  // logits: waves 0..7 compute logit wv
  if (wv < 8) {
    const int tb = tbw[g] - g * 64;
    const ushort* wr = WTa + (size_t)wv * 384;
    float part = 0.f;
    for (int k = lane; k < 384; k += 64) {
      float x = (k < 256) ? bf2f(Us[tb * HPP + k]) : Gs[k - 256];
      part += x * bf2f(wr[k]);
    }
#pragma unroll
    for (int o = 32; o > 0; o >>= 1) part += __shfl_down(part, o);
    if (lane == 0) Ls[wv] = part + ba[wv];
  }
  __syncthreads();

  if (tid == 0) {
    float mx = Ls[0];
#pragma unroll
    for (int i = 1; i < 8; ++i) mx = fmaxf(mx, Ls[i]);
    float e[8], sum = 0.f;
#pragma unroll
    for (int i = 0; i < 8; ++i) { e[i] = __expf(Ls[i] - mx); sum += e[i]; }
    float inv = 1.f / sum;
#pragma unroll
    for (int i = 0; i < 8; ++i) out[(size_t)g * 8 + i] = e[i] * inv;
  }
}

// ---------------- launch ----------------
extern "C" void kernel_launch(void* const* d_in, const int* in_sizes, int n_in,
                              void* d_out, int out_size, void* d_ws, size_t ws_size,
                              hipStream_t stream) {
  (void)in_sizes; (void)n_in; (void)out_size; (void)ws_size;
  using namespace cfg;
  const float* nodes = (const float*)d_in[0];
  const float* eattr = (const float*)d_in[1];
  const float* glob  = (const float*)d_in[2];
  const int* srci = (const int*)d_in[3];
  const int* tgti = (const int*)d_in[4];
  const int* tbw  = (const int*)d_in[7];
  const float* W_m0 = (const float*)d_in[8];
  const float* b_m0 = (const float*)d_in[9];
  const float* W_m1 = (const float*)d_in[10];
  const float* b_m1 = (const float*)d_in[11];
  const float* W_u0 = (const float*)d_in[12];
  const float* b_u0 = (const float*)d_in[13];
  const float* W_u1 = (const float*)d_in[14];
  const float* b_u1 = (const float*)d_in[15];
  const float* W_g  = (const float*)d_in[16];
  const float* b_g  = (const float*)d_in[17];
  const float* W_a  = (const float*)d_in[18];
  const float* b_a  = (const float*)d_in[19];

  char* ws = (char*)d_ws;
  size_t off = 0;
  auto alloc = [&](size_t bytes) {
    char* p = ws + off; off += (bytes + 255) & ~(size_t)255; return p;
  };
  ushort* WTm0 = (ushort*)alloc((size_t)512 * 384 * 2);
  ushort* WTm1 = (ushort*)alloc((size_t)256 * 512 * 2);
  ushort* WTu0 = (ushort*)alloc((size_t)512 * 448 * 2);
  ushort* WTu1 = (ushort*)alloc((size_t)256 * 512 * 2);
  ushort* WTg  = (ushort*)alloc((size_t)128 * 320 * 2);
  ushort* WTa  = (ushort*)alloc((size_t)8 * 384 * 2);

  dim3 tb(256);
  auto T = [&](const float* in, ushort* outp, int R, int C) {
    ktrans_cvt<<<dim3((C + 31) / 32, (R + 31) / 32), tb, 0, stream>>>(in, outp, R, C);
  };
  T(W_m0, WTm0, 384, 512);
  T(W_m1, WTm1, 512, 256);
  T(W_u0, WTu0, 448, 512);
  T(W_u1, WTu1, 512, 256);
  T(W_g,  WTg,  320, 128);
  T(W_a,  WTa,  384, 8);

  hipFuncSetAttribute((const void*)k_fused, hipFuncAttributeMaxDynamicSharedMemorySize,
                      (int)LDS_TOTAL);
  k_fused<<<NB, 1024, LDS_TOTAL, stream>>>(nodes, eattr, glob, srci, tgti, tbw,
                                           WTm0, b_m0, WTm1, b_m1,
                                           WTu0, b_u0, WTu1, b_u1,
                                           WTg, b_g, WTa, b_a, (float*)d_out);
}